// Round 12
// baseline (631.138 us; speedup 1.0000x reference)
//
#include <hip/hip_runtime.h>
#include <hip/hip_fp16.h>
#include <cmath>

// Problem constants
constexpr int B_ = 64, N_ = 50000, L_ = 8, E_ = 100000, U_ = 20000, G_ = 20000, R_ = 64, D_ = 16, C_ = 2;
constexpr int EPL_ = E_ + 3 * U_ + 4096;  // padded edge slots per layer (+slack for empty-u forced pad)
constexpr int NGRP_ = EPL_ / 4;           // edge groups per layer
constexpr int EPLG_ = NGRP_ + 16;         // ug table slots per layer
constexpr int GPW = 4;                    // groups per wave (16 edges) — balanced spans
constexpr int NSPAN_ = (NGRP_ + GPW - 1) / GPW;  // wave-spans per layer
constexpr int BC = 64;                    // whole batch in one chunk
constexpr int F = BC * 2;                 // float4 chunks per node row (2 KB, fp16)

// h fp16 layout: h[node][b][d], d-contiguous. chunk f = b*2 + dh.
// Node N_ is a reserved all-zero row (padding target).
// ug[g] = u owning edge-group g (groups never straddle u's); -1 past the end.
// spantab[li][w] = (first group in span owned by a u starting there, that u) or (-1,-1).

__device__ __forceinline__ float tanh_fast(float x) {
  float e = __expf(2.0f * x);
  return 1.0f - 2.0f * __builtin_amdgcn_rcpf(e + 1.0f);
}

// ---------------- CSR build (batch-independent) ----------------

__global__ __launch_bounds__(256) void hist_kernel(
    const int* __restrict__ dst_pos, int* __restrict__ cnt,
    int* __restrict__ rank) {
  int e = blockIdx.x * 256 + threadIdx.x;
  int li = blockIdx.y;
  if (e >= E_) return;
  rank[li * E_ + e] = atomicAdd(&cnt[li * U_ + dst_pos[li * E_ + e]], 1);
}

// Fast scan; counts padded to mult of 4, empty u's forced to 4 slots.
__global__ __launch_bounds__(1024) void scan_kernel(
    const int* __restrict__ cnt, int* __restrict__ offs) {
  __shared__ int sums[1024];
  int li = blockIdx.x, t = threadIdx.x;
  int base = t * 20;
  int v[20];
  int s = 0;
#pragma unroll
  for (int i = 0; i < 20; ++i) {
    int idx = base + i;
    int c = (idx < U_) ? cnt[li * U_ + idx] : -1;
    int pc = (c < 0) ? 0 : ((c == 0) ? 4 : ((c + 3) & ~3));
    v[i] = s;
    s += pc;
  }
  sums[t] = s;
  __syncthreads();
  for (int off = 1; off < 1024; off <<= 1) {
    int o = (t >= off) ? sums[t - off] : 0;
    __syncthreads();
    sums[t] += o;
    __syncthreads();
  }
  int excl = sums[t] - s;
#pragma unroll
  for (int i = 0; i < 20; ++i) {
    int idx = base + i;
    if (idx < U_) offs[li * (U_ + 1) + idx] = excl + v[i];
  }
  if (t == 1023) offs[li * (U_ + 1) + U_] = sums[1023];
}

// Atomic-free scatter: position = offs[u] + precomputed rank.
__global__ __launch_bounds__(256) void scatter_kernel(
    const int* __restrict__ dst_pos, const int* __restrict__ src,
    const int* __restrict__ offs, const int* __restrict__ rank,
    int* __restrict__ ssrc) {
  int e = blockIdx.x * 256 + threadIdx.x;
  int li = blockIdx.y;
  if (e >= E_) return;
  int u = dst_pos[li * E_ + e];
  int p = offs[li * (U_ + 1) + u] + rank[li * E_ + e];
  ssrc[(size_t)li * EPL_ + p] = src[li * E_ + e];
}

// Pad sentinel edges + build ug (group -> u) table. ug pre-memset to -1.
__global__ __launch_bounds__(256) void pad_fill_ug_k(
    const int* __restrict__ cnt, const int* __restrict__ offs,
    int* __restrict__ ssrc, int* __restrict__ ug) {
  int t = blockIdx.x * 256 + threadIdx.x;
  if (t >= L_ * U_) return;
  int li = t / U_, u = t % U_;
  int start = offs[li * (U_ + 1) + u];
  int end = start + cnt[li * U_ + u];       // real end
  int pend = offs[li * (U_ + 1) + u + 1];   // padded end
  int* sp = ssrc + (size_t)li * EPL_;
  for (int p = end; p < pend; ++p) sp[p] = N_;
  int* ugp = ug + (size_t)li * EPLG_;
  for (int g = start >> 2; g < (pend >> 2); ++g) ugp[g] = u;
  if (u == U_ - 1) {  // 8-int sentinel tail so prefetch never reads junk
    int ptot = offs[li * (U_ + 1) + U_];
    for (int p = ptot; p < ptot + 8; ++p) sp[p] = N_;
  }
}

// Span-start table: replaces gather's serial prologue scan with one 8B load.
__global__ __launch_bounds__(256) void spanstart_k(
    const int* __restrict__ ug, int2* __restrict__ spantab) {
  int t = blockIdx.x * 256 + threadIdx.x;
  if (t >= L_ * NSPAN_) return;
  int li = t / NSPAN_, w = t % NSPAN_;
  const int* ugp = ug + (size_t)li * EPLG_;
  int g0 = w * GPW, gend = g0 + GPW;
  int prevU = (g0 == 0) ? -2 : ugp[g0 - 1];
  int g = g0;
  while (g < gend && ugp[g] == prevU) ++g;
  int cu = (g < gend) ? ugp[g] : -1;
  spantab[t] = (g < gend && cu >= 0) ? make_int2(g, cu) : make_int2(-1, -1);
}

// ---------------- Compute ----------------

// Coalesced gene init: block loads a 64x64 X tile (coalesced rows), transposes
// in LDS, then each wave writes 16 gene rows (2KB contiguous each).
__global__ __launch_bounds__(256) void gene_init_k(
    const float* __restrict__ X, const float* __restrict__ w_in,
    const float* __restrict__ b_in, const int* __restrict__ gene_map,
    float4* __restrict__ h4) {
  __shared__ float xt[64][65];  // [g_off][b], 65-stride pad
  int t = threadIdx.x;
  int g0 = blockIdx.x * 64;
  int col = t & 63, rowb = t >> 6;
#pragma unroll
  for (int i = 0; i < 16; ++i) {
    int b = i * 4 + rowb;
    int g = g0 + col;
    xt[col][b] = (g < G_) ? X[b * G_ + g] : 0.f;  // coalesced 256B row reads
  }
  __syncthreads();
  float wv[16], bv[16];
#pragma unroll
  for (int k = 0; k < 16; ++k) { wv[k] = w_in[k]; bv[k] = b_in[k]; }
  int wave = t >> 6, lane = t & 63;
#pragma unroll
  for (int i = 0; i < 16; ++i) {
    int g = g0 + wave * 16 + i;
    if (g >= G_) break;  // wave-uniform
    float x = xt[g - g0][lane];
    int node = gene_map[g];  // wave-uniform
    float4 out[2];
    __half2* oh = reinterpret_cast<__half2*>(out);
#pragma unroll
    for (int k = 0; k < 8; ++k) {
      float r0 = fmaf(x, wv[2 * k], bv[2 * k]);
      float r1 = fmaf(x, wv[2 * k + 1], bv[2 * k + 1]);
      oh[k] = __float22half2_rn(make_float2(r0, r1));
    }
    h4[(size_t)node * F + lane * 2] = out[0];
    h4[(size_t)node * F + lane * 2 + 1] = out[1];
  }
}

// Balanced gather-sum: each wave owns GPW consecutive edge-groups; span start
// comes from spantab (no serial prologue). Processes every u STARTING in its
// span to completion (running past the span end if needed). 2-deep ping-pong
// row pipeline; fp16 packed accumulation.
__global__ __launch_bounds__(256) void gather_k(
    const float4* __restrict__ h4, const int* __restrict__ ug,
    const int2* __restrict__ spantab, const int* __restrict__ ssrc,
    float4* __restrict__ agg4, int li) {
  int tid = threadIdx.x;
  int wave = tid >> 6, lane = tid & 63;
  int wv = blockIdx.x * 4 + wave;
  int2 sc = spantab[li * NSPAN_ + wv];
  if (sc.x < 0) return;
  int g = sc.x, curU = sc.y;
  int gend = wv * GPW + GPW;
  const int* ugp = ug + (size_t)li * EPLG_;
  const int* sp = ssrc + (size_t)li * EPL_;

  __half2 acc[2][2][4];
  const __half2 z = __half2half2(__float2half(0.f));
#pragma unroll
  for (int j = 0; j < 2; ++j)
#pragma unroll
    for (int r = 0; r < 2; ++r)
#pragma unroll
      for (int k = 0; k < 4; ++k) acc[j][r][k] = z;

  auto flushu = [&](int u) {
#pragma unroll
    for (int r = 0; r < 2; ++r) {
      float4 outv;
      __half2* ov = reinterpret_cast<__half2*>(&outv);
#pragma unroll
      for (int k = 0; k < 4; ++k) {
        float2 f0 = __half22float2(acc[0][r][k]);
        float2 f1 = __half22float2(acc[1][r][k]);
        ov[k] = __float22half2_rn(make_float2(f0.x + f1.x, f0.y + f1.y));
      }
      agg4[(size_t)u * F + lane + r * 64] = outv;
    }
#pragma unroll
    for (int j = 0; j < 2; ++j)
#pragma unroll
      for (int r = 0; r < 2; ++r)
#pragma unroll
        for (int k = 0; k < 4; ++k) acc[j][r][k] = z;
  };

  auto loadRows = [&](float4 (&v)[4][2], int4 id) {
    v[0][0] = h4[(size_t)id.x * F + lane]; v[0][1] = h4[(size_t)id.x * F + lane + 64];
    v[1][0] = h4[(size_t)id.y * F + lane]; v[1][1] = h4[(size_t)id.y * F + lane + 64];
    v[2][0] = h4[(size_t)id.z * F + lane]; v[2][1] = h4[(size_t)id.z * F + lane + 64];
    v[3][0] = h4[(size_t)id.w * F + lane]; v[3][1] = h4[(size_t)id.w * F + lane + 64];
  };
  auto accum = [&](const float4 (&v)[4][2]) {
#pragma unroll
    for (int j = 0; j < 4; ++j)
#pragma unroll
      for (int r = 0; r < 2; ++r) {
        const __half2* p = reinterpret_cast<const __half2*>(&v[j][r]);
#pragma unroll
        for (int k = 0; k < 4; ++k)
          acc[j & 1][r][k] = __hadd2(acc[j & 1][r][k], p[k]);
      }
  };

  float4 va[4][2], vb[4][2];
  int4 idA = *(const int4*)(sp + 4 * g);
  loadRows(va, idA);
  int nuA = ugp[g + 1];
  int nuB;

  for (;;) {
    // phase A: current group in va
    {
      bool more = (nuA >= 0) && ((nuA == curU) || (g + 1 < gend));
      if (more) {
        int4 idB = *(const int4*)(sp + 4 * (g + 1));
        loadRows(vb, idB);
        nuB = ugp[g + 2];
      }
      accum(va);
      if (nuA != curU) {
        flushu(curU);
        if (!more) return;
        curU = nuA;
      }
      ++g;
    }
    // phase B: current group in vb
    {
      bool more = (nuB >= 0) && ((nuB == curU) || (g + 1 < gend));
      if (more) {
        int4 idA2 = *(const int4*)(sp + 4 * (g + 1));
        loadRows(va, idA2);
        nuA = ugp[g + 2];
      }
      accum(vb);
      if (nuB != curU) {
        flushu(curU);
        if (!more) return;
        curU = nuB;
      }
      ++g;
    }
  }
}

// Dense epilogue: one thread per (u,b). All-static indexing (no scratch).
__global__ __launch_bounds__(256) void dense_k(
    const float4* __restrict__ agg4, const float* __restrict__ W,
    const float* __restrict__ bias, const int* __restrict__ dst_unique,
    float4* __restrict__ h4, int li) {
  __shared__ float Wlds[256];
  int tid = threadIdx.x;
  Wlds[tid] = W[li * 256 + tid];
  __syncthreads();
  int t = blockIdx.x * 256 + tid;
  int u = t >> 6, b = t & 63;
  float4 c0 = agg4[(size_t)u * F + b * 2];
  float4 c1 = agg4[(size_t)u * F + b * 2 + 1];
  float a[16];
  {
    const __half2* p0 = reinterpret_cast<const __half2*>(&c0);
    const __half2* p1 = reinterpret_cast<const __half2*>(&c1);
#pragma unroll
    for (int k = 0; k < 4; ++k) {
      float2 f0 = __half22float2(p0[k]);
      float2 f1 = __half22float2(p1[k]);
      a[2 * k] = f0.x; a[2 * k + 1] = f0.y;
      a[8 + 2 * k] = f1.x; a[8 + 2 * k + 1] = f1.y;
    }
  }
  float m[16];
#pragma unroll
  for (int j = 0; j < 16; ++j) m[j] = 0.f;
#pragma unroll
  for (int d = 0; d < 16; ++d) {
    float s = a[d];
    const float4* wr = (const float4*)&Wlds[d * 16];  // broadcast reads (free)
    float4 w0 = wr[0], w1 = wr[1], w2 = wr[2], w3 = wr[3];
    m[0] = fmaf(s, w0.x, m[0]);  m[1] = fmaf(s, w0.y, m[1]);
    m[2] = fmaf(s, w0.z, m[2]);  m[3] = fmaf(s, w0.w, m[3]);
    m[4] = fmaf(s, w1.x, m[4]);  m[5] = fmaf(s, w1.y, m[5]);
    m[6] = fmaf(s, w1.z, m[6]);  m[7] = fmaf(s, w1.w, m[7]);
    m[8] = fmaf(s, w2.x, m[8]);  m[9] = fmaf(s, w2.y, m[9]);
    m[10] = fmaf(s, w2.z, m[10]); m[11] = fmaf(s, w2.w, m[11]);
    m[12] = fmaf(s, w3.x, m[12]); m[13] = fmaf(s, w3.y, m[13]);
    m[14] = fmaf(s, w3.z, m[14]); m[15] = fmaf(s, w3.w, m[15]);
  }
  int node = dst_unique[li * U_ + u];  // wave-uniform
  const float4* bp = (const float4*)(bias + (size_t)node * 16);
  float4 b0 = bp[0], b1 = bp[1], b2 = bp[2], b3 = bp[3];
  float bb[16] = {b0.x, b0.y, b0.z, b0.w, b1.x, b1.y, b1.z, b1.w,
                  b2.x, b2.y, b2.z, b2.w, b3.x, b3.y, b3.z, b3.w};
  float4 o0, o1;
  __half2* ov0 = reinterpret_cast<__half2*>(&o0);
  __half2* ov1 = reinterpret_cast<__half2*>(&o1);
#pragma unroll
  for (int k = 0; k < 4; ++k) {
    ov0[k] = __float22half2_rn(make_float2(tanh_fast(m[2 * k] + bb[2 * k]),
                                           tanh_fast(m[2 * k + 1] + bb[2 * k + 1])));
    ov1[k] = __float22half2_rn(make_float2(tanh_fast(m[8 + 2 * k] + bb[8 + 2 * k]),
                                           tanh_fast(m[8 + 2 * k + 1] + bb[8 + 2 * k + 1])));
  }
  h4[(size_t)node * F + b * 2] = o0;
  h4[(size_t)node * F + b * 2 + 1] = o1;
}

__global__ __launch_bounds__(64) void head_k(
    const float4* __restrict__ h4, const float* __restrict__ W_head,
    const float* __restrict__ b_head, const int* __restrict__ root_ids,
    float* __restrict__ out) {
  int bl = blockIdx.x;
  int r = threadIdx.x;
  int node = root_ids[r];
  float4 p0 = h4[(size_t)node * F + bl * 2];
  float4 p1 = h4[(size_t)node * F + bl * 2 + 1];
  float v[16];
  const __half2* ph0 = reinterpret_cast<const __half2*>(&p0);
  const __half2* ph1 = reinterpret_cast<const __half2*>(&p1);
#pragma unroll
  for (int k = 0; k < 4; ++k) {
    float2 f0 = __half22float2(ph0[k]);
    float2 f1 = __half22float2(ph1[k]);
    v[2 * k] = f0.x; v[2 * k + 1] = f0.y;
    v[8 + 2 * k] = f1.x; v[8 + 2 * k + 1] = f1.y;
  }
  float acc0 = 0.f, acc1 = 0.f;
#pragma unroll
  for (int d = 0; d < 16; ++d) {
    acc0 = fmaf(v[d], W_head[r * 16 + d], acc0);
    acc1 = fmaf(v[d], W_head[1024 + r * 16 + d], acc1);
  }
  for (int off = 32; off; off >>= 1) {
    acc0 += __shfl_down(acc0, off, 64);
    acc1 += __shfl_down(acc1, off, 64);
  }
  if (r == 0) {
    out[bl * 2 + 0] = acc0 + b_head[0];
    out[bl * 2 + 1] = acc1 + b_head[1];
  }
}

__global__ void zero_out_k(float* out, int n) {
  int t = blockIdx.x * 256 + threadIdx.x;
  if (t < n) out[t] = 0.f;
}

// ---------------- Host side ----------------

static size_t need_bytes() {
  return (size_t)(N_ + 1) * F * 16 + (size_t)U_ * F * 16 +
         (size_t)L_ * U_ * 4 +            // cnt
         (size_t)L_ * (U_ + 1) * 4 +      // offs
         (size_t)L_ * E_ * 4 +            // rank (aliased: ug + spantab after scatter)
         (size_t)L_ * EPL_ * 4;           // ssrc
}

extern "C" void kernel_launch(void* const* d_in, const int* in_sizes, int n_in,
                              void* d_out, int out_size, void* d_ws, size_t ws_size,
                              hipStream_t stream) {
  if (ws_size < need_bytes()) {
    zero_out_k<<<(out_size + 255) / 256, 256, 0, stream>>>((float*)d_out, out_size);
    return;
  }
  const float* X = (const float*)d_in[0];
  const float* w_in = (const float*)d_in[1];
  const float* b_in = (const float*)d_in[2];
  const float* W = (const float*)d_in[3];
  const float* bias = (const float*)d_in[4];
  const float* W_head = (const float*)d_in[5];
  const float* b_head = (const float*)d_in[6];
  const int* gene_map = (const int*)d_in[7];
  const int* src = (const int*)d_in[8];
  const int* dst_pos = (const int*)d_in[9];
  const int* dst_unique = (const int*)d_in[10];
  const int* root_ids = (const int*)d_in[11];
  float* out = (float*)d_out;

  const size_t h_bytes = (size_t)(N_ + 1) * F * 16;   // + zero sentinel row
  const size_t agg_bytes = (size_t)U_ * F * 16;
  const size_t cnt_bytes = (size_t)L_ * U_ * 4;
  const size_t offs_bytes = (size_t)L_ * (U_ + 1) * 4;
  const size_t rank_bytes = (size_t)L_ * E_ * 4;
  const size_t ug_bytes = (size_t)L_ * EPLG_ * 4;     // 1.31 MB
  const size_t stab_bytes = (size_t)L_ * NSPAN_ * 8;  // 0.66 MB (ug+stab <= rank)

  char* ws = (char*)d_ws;
  float4* h4 = (float4*)ws;
  float4* agg4 = (float4*)(ws + h_bytes);
  int* cnt = (int*)(ws + h_bytes + agg_bytes);
  int* offs = (int*)(ws + h_bytes + agg_bytes + cnt_bytes);
  int* rank = (int*)(ws + h_bytes + agg_bytes + cnt_bytes + offs_bytes);
  int* ug = rank;                               // alias: rank dead after scatter
  int2* spantab = (int2*)((char*)rank + ug_bytes);
  int* ssrc = (int*)(ws + h_bytes + agg_bytes + cnt_bytes + offs_bytes + rank_bytes);
  (void)stab_bytes;

  hipMemsetAsync(cnt, 0, cnt_bytes, stream);
  hipMemsetAsync(h4, 0, h_bytes, stream);
  dim3 egrid((E_ + 255) / 256, L_);
  hist_kernel<<<egrid, 256, 0, stream>>>(dst_pos, cnt, rank);
  scan_kernel<<<L_, 1024, 0, stream>>>(cnt, offs);
  scatter_kernel<<<egrid, 256, 0, stream>>>(dst_pos, src, offs, rank, ssrc);
  hipMemsetAsync(ug, 0xFF, ug_bytes, stream);  // all -1 sentinels
  pad_fill_ug_k<<<(L_ * U_ + 255) / 256, 256, 0, stream>>>(cnt, offs, ssrc, ug);
  spanstart_k<<<(L_ * NSPAN_ + 255) / 256, 256, 0, stream>>>(ug, spantab);

  gene_init_k<<<(G_ + 63) / 64, 256, 0, stream>>>(X, w_in, b_in, gene_map, h4);

  const int gather_grid = (NSPAN_ + 3) / 4;
  const int dense_grid = U_ * BC / 256;
  for (int li = 0; li < L_; ++li) {
    gather_k<<<gather_grid, 256, 0, stream>>>(h4, ug, spantab, ssrc, agg4, li);
    dense_k<<<dense_grid, 256, 0, stream>>>(agg4, W, bias, dst_unique, h4, li);
  }

  head_k<<<BC, 64, 0, stream>>>(h4, W_head, b_head, root_ids, out);
}